// Round 1
// baseline (599.334 us; speedup 1.0000x reference)
//
#include <hip/hip_runtime.h>
#include <math.h>

#define BATCH 32
#define HH 1024
#define WW 1024
#define WR 513
#define NPIX (HH * WR)
#define TWO_PI_F 6.28318530717958647692f

// Same-wave LDS fence: each wave only touches its own LDS region, so a full
// block barrier is unnecessary — wait for this wave's own LDS ops instead.
#define LGKM_SYNC() __asm__ __volatile__("s_waitcnt lgkmcnt(0)" ::: "memory")

__device__ __forceinline__ float2 cadd(float2 a, float2 b) { return make_float2(a.x + b.x, a.y + b.y); }
__device__ __forceinline__ float2 csub(float2 a, float2 b) { return make_float2(a.x - b.x, a.y - b.y); }
__device__ __forceinline__ float2 cmul(float2 a, float2 b) {
    return make_float2(a.x * b.x - a.y * b.y, a.x * b.y + a.y * b.x);
}

// atan2 via odd minimax poly on [0,1] (max err ~1e-5 rad) + quadrant fixup.
__device__ __forceinline__ float fast_atan2f(float y, float x) {
    float ax = __builtin_fabsf(x), ay = __builtin_fabsf(y);
    float mx = fmaxf(ax, ay), mn = fminf(ax, ay);
    float a = mn * __builtin_amdgcn_rcpf(mx);
    float s = a * a;
    float r = fmaf(fmaf(fmaf(fmaf(0.0208351f, s, -0.085133f), s, 0.180141f),
                        s, -0.3302995f), s, 0.999866f) * a;
    if (ay > ax) r = 1.5707963268f - r;
    if (x < 0.0f) r = 3.1415926536f - r;
    return (y < 0.0f) ? -r : r;
}

// Natural-order 16-point FFT, in place, fully in registers (Stockham radix-4 x2).
__device__ __forceinline__ void fft16(float2* d) {
    float2 b[16];
#pragma unroll
    for (int t = 0; t < 4; ++t) {
        float2 x0 = d[t], x1 = d[t + 4], x2 = d[t + 8], x3 = d[t + 12];
        float2 a0 = cadd(x0, x2), a1 = csub(x0, x2), a2 = cadd(x1, x3), a3 = csub(x1, x3);
        b[4 * t + 0] = cadd(a0, a2);
        b[4 * t + 1] = make_float2(a1.x + a3.y, a1.y - a3.x);
        b[4 * t + 2] = csub(a0, a2);
        b[4 * t + 3] = make_float2(a1.x - a3.y, a1.y + a3.x);
    }
    const float2 W1[4] = {make_float2(1.0f, 0.0f),
                          make_float2(0.92387953f, -0.38268343f),
                          make_float2(0.70710678f, -0.70710678f),
                          make_float2(0.38268343f, -0.92387953f)};
#pragma unroll
    for (int t = 0; t < 4; ++t) {
        float2 w1 = W1[t], w2 = cmul(w1, w1), w3 = cmul(w2, w1);
        float2 x0 = b[t], x1 = cmul(b[t + 4], w1), x2 = cmul(b[t + 8], w2), x3 = cmul(b[t + 12], w3);
        float2 a0 = cadd(x0, x2), a1 = csub(x0, x2), a2 = cadd(x1, x3), a3 = csub(x1, x3);
        d[t + 0]  = cadd(a0, a2);
        d[t + 4]  = make_float2(a1.x + a3.y, a1.y - a3.x);
        d[t + 8]  = csub(a0, a2);
        d[t + 12] = make_float2(a1.x - a3.y, a1.y + a3.x);
    }
}

// Wave-level 1024-pt FFT. Input: v[j] = x[lane + 64*j]. sb = this wave's
// PRIVATE 1088-float LDS scratch. No block barriers — lgkmcnt fences only.
// Output: v[m] = X[(lane&15) + 16*m + 256*kq], kq = 2*((lane>>4)&1) + ((lane>>5)&1).
__device__ __forceinline__ void wave_fft1024(float2* v, float* sb, int lane) {
    fft16(v);
    float s, c;
    __sincosf(-TWO_PI_F * (float)lane * (1.0f / 1024.0f), &s, &c);
    float2 T = make_float2(c, s), w = T;
#pragma unroll
    for (int k2 = 1; k2 < 16; ++k2) { v[k2] = cmul(v[k2], w); w = cmul(w, T); }
    // 16x64 transpose, two b32 passes at stride 68 (bank-conflict-free)
    const int k2p = lane & 15, qp = lane >> 4;
    float tx[16];
#pragma unroll
    for (int k2 = 0; k2 < 16; ++k2) sb[68 * k2 + lane] = v[k2].x;
    LGKM_SYNC();
#pragma unroll
    for (int m = 0; m < 16; ++m) tx[m] = sb[68 * k2p + 4 * m + qp];
    LGKM_SYNC();
#pragma unroll
    for (int k2 = 0; k2 < 16; ++k2) sb[68 * k2 + lane] = v[k2].y;
    LGKM_SYNC();
#pragma unroll
    for (int m = 0; m < 16; ++m) v[m] = make_float2(tx[m], sb[68 * k2p + 4 * m + qp]);
    LGKM_SYNC();                       // scratch reusable by caller after return
    fft16(v);
    __sincosf(-TWO_PI_F * (float)qp * (1.0f / 64.0f), &s, &c);
    float2 U = make_float2(c, s);
    w = U;
#pragma unroll
    for (int km = 1; km < 16; ++km) { v[km] = cmul(v[km], w); w = cmul(w, U); }
    const bool hi2 = (lane & 32) != 0, hi1 = (lane & 16) != 0;
#pragma unroll
    for (int m = 0; m < 16; ++m) {
        float2 a = v[m];
        float2 o = make_float2(__shfl_xor(a.x, 32, 64), __shfl_xor(a.y, 32, 64));
        float2 s1 = hi2 ? csub(o, a) : cadd(a, o);
        if (hi2 && hi1) s1 = make_float2(s1.y, -s1.x);
        float2 o2 = make_float2(__shfl_xor(s1.x, 16, 64), __shfl_xor(s1.y, 16, 64));
        v[m] = hi1 ? csub(o2, s1) : cadd(s1, o2);
    }
}

// ---------------------------------------------------------------------------
// Kernel A: 4 waves/block, each wave = 2 packed real rows -> 1 complex FFT.
// One block barrier total (before the cross-wave transposed flush).
// LDS caps this kernel at 4 blocks/CU (34.8 KB/block), so 4 waves/EU is right.
// ---------------------------------------------------------------------------
__global__ __launch_bounds__(256, 4) void row_fft_kernel(const float* __restrict__ x,
                                                         float2* __restrict__ rf2) {
    __shared__ float2 buf[4 * 1088];
    const int t = threadIdx.x, w = t >> 6, lane = t & 63;
    const int b = blockIdx.x >> 7;
    const int h0 = (blockIdx.x & 127) * 8;
    const float* r0 = x + ((long long)b * HH + h0 + 2 * w) * (long long)WW;
    const float* r1 = r0 + WW;
    float2 v[16];
#pragma unroll
    for (int j = 0; j < 16; ++j) v[j] = make_float2(r0[lane + 64 * j], r1[lane + 64 * j]);
    float2* mybuf = buf + w * 1088;
    wave_fft1024(v, (float*)mybuf, lane);
    const int kq = 2 * ((lane >> 4) & 1) + ((lane >> 5) & 1);
    const int kbase = (lane & 15) + 256 * kq;
#pragma unroll
    for (int m = 0; m < 16; ++m) mybuf[kbase + 16 * m] = v[m];
    __syncthreads();
    for (int idx = t; idx < 513 * 8; idx += 256) {
        int k = idx >> 3, j = idx & 7, p = j >> 1, which = j & 1;
        float2 zk = buf[p * 1088 + k];
        float2 zn = buf[p * 1088 + ((1024 - k) & 1023)];
        float2 val = which ? make_float2(0.5f * (zk.y + zn.y), 0.5f * (zn.x - zk.x))
                           : make_float2(0.5f * (zk.x + zn.x), 0.5f * (zk.y - zn.y));
        rf2[((long long)b * WR + k) * 1024 + h0 + j] = val;
    }
}

// ---------------------------------------------------------------------------
// Kernel B: 2 waves/block, each wave = one contiguous 8KB row FFT of rf2[b][k][:].
// Barrier-free; 8.7 KB LDS/block. Phase into floats 0..1023 of the row
// (floats 1024..2047 = dead space reused by stats partials).
// launch_bounds(128,8): kernel is latency-bound (VALUBusy 19%, HBM 11%,
// occ 33% at the old (128,4) cap); it uses exactly 64 VGPR = the 8-waves/EU
// budget, and LDS allows 16 blocks/CU — so double the resident waves.
// ---------------------------------------------------------------------------
__global__ __launch_bounds__(128, 8) void col_fft_kernel(float2* __restrict__ rf2,
                                                         float* __restrict__ magmax) {
    __shared__ float sb[2 * 1088];
    const int t = threadIdx.x, w = t >> 6, lane = t & 63;
    const int fid = blockIdx.x * 2 + w;
    const int b = fid / WR, k = fid - b * WR;
    float2* row = rf2 + ((long long)b * WR + k) * 1024;
    float2 v[16];
#pragma unroll
    for (int j = 0; j < 16; ++j) v[j] = row[lane + 64 * j];
    wave_fft1024(v, sb + w * 1088, lane);
    float* pu = (float*)row;
    const int kq = 2 * ((lane >> 4) & 1) + ((lane >> 5) & 1);
    const int hbase = (lane & 15) + 256 * kq;
    float mmax = 0.0f;
#pragma unroll
    for (int m = 0; m < 16; ++m) {
        float2 z = v[m];
        mmax = fmaxf(mmax, __builtin_amdgcn_sqrtf(z.x * z.x + z.y * z.y));
        float ph = fast_atan2f(z.y, z.x);
        pu[hbase + 16 * m] = (ph < 0.0f) ? ph + TWO_PI_F : ph;
    }
#pragma unroll
    for (int off = 32; off; off >>= 1) mmax = fmaxf(mmax, __shfl_down(mmax, off));
    if (lane == 0) atomicMax((int*)(magmax + b), __float_as_int(mmax));
}

// ---------------------------------------------------------------------------
// Kernel C: single-pass gradients + all 55 Zernike moments + mask count.
// No atomics: wave shuffle-reduce -> LDS -> per-block 60-float partial into
// the dead upper half of pu row (b*57 + blockIdx.x).
// launch_bounds(256,3): was (256,2) = 25% occupancy cap; 3 waves/EU keeps
// the VGPR cap at ~168 (no spill risk for ~120 live regs) and gives +50%
// resident waves for load-latency hiding.
// ---------------------------------------------------------------------------
#define WRED(var, idx)                                                     \
    {                                                                      \
        float r_ = var;                                                    \
        _Pragma("unroll")                                                  \
        for (int off_ = 32; off_; off_ >>= 1) r_ += __shfl_down(r_, off_); \
        if (lane == 0) red[wv * 64 + (idx)] = r_;                          \
    }

__global__ __launch_bounds__(256, 3) void stats_kernel(float* __restrict__ pu) {
    __shared__ float red[4 * 64];
    const int b = blockIdx.y;
    const int k0 = blockIdx.x * 9;
    const float* base = pu + (long long)b * WR * 2048;
    float a00 = 0.f, a11 = 0.f, a20 = 0.f, a22 = 0.f, a31 = 0.f, a33 = 0.f,
          a40 = 0.f, a42 = 0.f, a44 = 0.f, a51 = 0.f, a53 = 0.f, a55 = 0.f,
          a60 = 0.f, a62 = 0.f, a64 = 0.f, a66 = 0.f, a71 = 0.f, a73 = 0.f,
          a75 = 0.f, a77 = 0.f, a80 = 0.f, a82 = 0.f, a84 = 0.f, a86 = 0.f,
          a88 = 0.f, a91 = 0.f, a93 = 0.f, a95 = 0.f, a97 = 0.f, a99 = 0.f;
    float b11 = 0.f, b22 = 0.f, b31 = 0.f, b33 = 0.f, b42 = 0.f, b44 = 0.f,
          b51 = 0.f, b53 = 0.f, b55 = 0.f, b62 = 0.f, b64 = 0.f, b66 = 0.f,
          b71 = 0.f, b73 = 0.f, b75 = 0.f, b77 = 0.f, b82 = 0.f, b84 = 0.f,
          b86 = 0.f, b88 = 0.f, b91 = 0.f, b93 = 0.f, b95 = 0.f, b97 = 0.f,
          b99 = 0.f;
    float sgx = 0.f, sgx2 = 0.f, sgy = 0.f, sgy2 = 0.f, cnt = 0.f;

    for (int kk = 0; kk < 9; ++kk) {
        const int k = k0 + kk;
        const float* rowc = base + (long long)k * 2048;
        const float* rowm = rowc - 2048;
        const float* rowp = rowc + 2048;
        const float xv = -1.0f + (1.0f / 256.0f) * (float)k;
        const float xv2 = xv * xv;
        for (int h = threadIdx.x; h < 1024; h += 256) {
            float v = rowc[h];
            float gx, gy;
            if (k == 0)            gx = rowp[h] - v;
            else if (k == WR - 1)  gx = v - rowm[h];
            else                   gx = 0.5f * (rowp[h] - rowm[h]);
            if (h == 0)            gy = rowc[1] - v;
            else if (h == 1023)    gy = v - rowc[1022];
            else                   gy = 0.5f * (rowc[h + 1] - rowc[h - 1]);
            sgx += gx; sgx2 += gx * gx; sgy += gy; sgy2 += gy * gy;

            const float yv = -1.0f + (2.0f / 1023.0f) * (float)h;
            const float r2 = xv2 + yv * yv;
            if (r2 <= 1.0f) {
                cnt += 1.0f;
                const float rho = sqrtf(r2);
                const float inv = rsqrtf(r2);
                const float c1 = xv * inv;
                const float s1 = yv * inv;
                const float c2 = 2.f * c1 * c1 - 1.f;
                const float c3 = 2.f * c1 * c2 - c1;
                const float c4 = 2.f * c1 * c3 - c2;
                const float c5 = 2.f * c1 * c4 - c3;
                const float c6 = 2.f * c1 * c5 - c4;
                const float c7 = 2.f * c1 * c6 - c5;
                const float c8 = 2.f * c1 * c7 - c6;
                const float c9 = 2.f * c1 * c8 - c7;
                const float s2 = 2.f * c1 * s1;
                const float s3 = 2.f * c1 * s2 - s1;
                const float s4 = 2.f * c1 * s3 - s2;
                const float s5 = 2.f * c1 * s4 - s3;
                const float s6 = 2.f * c1 * s5 - s4;
                const float s7 = 2.f * c1 * s6 - s5;
                const float s8 = 2.f * c1 * s7 - s6;
                const float s9 = 2.f * c1 * s8 - s7;
                const float w0 = v,        w1 = w0 * rho, w2 = w1 * rho, w3 = w2 * rho,
                            w4 = w3 * rho, w5 = w4 * rho, w6 = w5 * rho, w7 = w6 * rho,
                            w8 = w7 * rho, w9 = w8 * rho;
                a00 += w0;
                a11 += w1 * c1;
                a20 += w2;      a22 += w2 * c2;
                a31 += w3 * c1; a33 += w3 * c3;
                a40 += w4;      a42 += w4 * c2; a44 += w4 * c4;
                a51 += w5 * c1; a53 += w5 * c3; a55 += w5 * c5;
                a60 += w6;      a62 += w6 * c2; a64 += w6 * c4; a66 += w6 * c6;
                a71 += w7 * c1; a73 += w7 * c3; a75 += w7 * c5; a77 += w7 * c7;
                a80 += w8;      a82 += w8 * c2; a84 += w8 * c4; a86 += w8 * c6; a88 += w8 * c8;
                a91 += w9 * c1; a93 += w9 * c3; a95 += w9 * c5; a97 += w9 * c7; a99 += w9 * c9;
                b11 += w1 * s1;
                b22 += w2 * s2;
                b31 += w3 * s1; b33 += w3 * s3;
                b42 += w4 * s2; b44 += w4 * s4;
                b51 += w5 * s1; b53 += w5 * s3; b55 += w5 * s5;
                b62 += w6 * s2; b64 += w6 * s4; b66 += w6 * s6;
                b71 += w7 * s1; b73 += w7 * s3; b75 += w7 * s5; b77 += w7 * s7;
                b82 += w8 * s2; b84 += w8 * s4; b86 += w8 * s6; b88 += w8 * s8;
                b91 += w9 * s1; b93 += w9 * s3; b95 += w9 * s5; b97 += w9 * s7; b99 += w9 * s9;
            }
        }
    }

    const int wv = threadIdx.x >> 6, lane = threadIdx.x & 63;
    WRED(a00, 0);  WRED(a11, 1);  WRED(a20, 2);  WRED(a22, 3);  WRED(a31, 4);
    WRED(a33, 5);  WRED(a40, 6);  WRED(a42, 7);  WRED(a44, 8);  WRED(a51, 9);
    WRED(a53, 10); WRED(a55, 11); WRED(a60, 12); WRED(a62, 13); WRED(a64, 14);
    WRED(a66, 15); WRED(a71, 16); WRED(a73, 17); WRED(a75, 18); WRED(a77, 19);
    WRED(a80, 20); WRED(a82, 21); WRED(a84, 22); WRED(a86, 23); WRED(a88, 24);
    WRED(a91, 25); WRED(a93, 26); WRED(a95, 27); WRED(a97, 28); WRED(a99, 29);
    WRED(b11, 30); WRED(b22, 31); WRED(b31, 32); WRED(b33, 33); WRED(b42, 34);
    WRED(b44, 35); WRED(b51, 36); WRED(b53, 37); WRED(b55, 38); WRED(b62, 39);
    WRED(b64, 40); WRED(b66, 41); WRED(b71, 42); WRED(b73, 43); WRED(b75, 44);
    WRED(b77, 45); WRED(b82, 46); WRED(b84, 47); WRED(b86, 48); WRED(b88, 49);
    WRED(b91, 50); WRED(b93, 51); WRED(b95, 52); WRED(b97, 53); WRED(b99, 54);
    WRED(sgx, 55); WRED(sgx2, 56); WRED(sgy, 57); WRED(sgy2, 58); WRED(cnt, 59);
    __syncthreads();
    const int t = threadIdx.x;
    if (t < 60) {
        float s = red[t] + red[64 + t] + red[128 + t] + red[192 + t];
        pu[((long long)(b * 57 + blockIdx.x)) * 2048 + 1024 + t] = s;
    }
}

// ---------------------------------------------------------------------------
// Kernel D: sum 57 block-partials per batch, map moments -> Zernike coeffs,
// finalize stats.
// ---------------------------------------------------------------------------
__device__ int moment_index(int p, int a, int is_cos) {
    int ai = 0;
    for (int pp = 0; pp < 10; ++pp)
        for (int aa = (pp & 1); aa <= pp; aa += 2) {
            if (is_cos && pp == p && aa == a) return ai;
            ++ai;
        }
    for (int pp = 1; pp < 10; ++pp)
        for (int aa = ((pp & 1) ? 1 : 2); aa <= pp; aa += 2) {
            if (!is_cos && pp == p && aa == a) return ai;
            ++ai;
        }
    return 0;
}

__device__ float factf(int n) {
    float f = 1.0f;
    for (int i = 2; i <= n; ++i) f *= (float)i;
    return f;
}

__global__ void finalize_kernel(const float* __restrict__ pu,
                                const float* __restrict__ magmax,
                                float* __restrict__ out) {
    __shared__ float abf[64];
    const int b = blockIdx.x;
    const int j = threadIdx.x;
    if (j < 60) {
        float s = 0.0f;
        for (int i = 0; i < 57; ++i)
            s += pu[((long long)(b * 57 + i)) * 2048 + 1024 + j];
        abf[j] = s;
    }
    __syncthreads();
    if (j >= 60) return;
    const float NF = (float)NPIX;
    float val;
    if (j < 55) {
        int tt = j, n = 0;
        while (tt >= n + 1) { tt -= (n + 1); ++n; }
        int m = -n + 2 * tt;
        int am = m < 0 ? -m : m;
        float s = 0.0f;
        for (int k = 0; k <= (n - am) / 2; ++k) {
            float c = factf(n - k) /
                      (factf(k) * factf((n + am) / 2 - k) * factf((n - am) / 2 - k));
            if (k & 1) c = -c;
            int p = n - 2 * k;
            s += c * abf[moment_index(p, am, m >= 0 ? 1 : 0)];
        }
        val = s / abf[59];
    } else if (j == 55) {
        val = abf[55] / NF;
    } else if (j == 56) {
        val = abf[57] / NF;
    } else if (j == 57) {
        float sum = abf[55], sq = abf[56];
        val = sqrtf(fmaxf(0.0f, (sq - sum * sum / NF) / (NF - 1.0f)));
    } else if (j == 58) {
        float sum = abf[57], sq = abf[58];
        val = sqrtf(fmaxf(0.0f, (sq - sum * sum / NF) / (NF - 1.0f)));
    } else {
        val = magmax[b];
    }
    out[b * 60 + j] = val;
}

// ---------------------------------------------------------------------------
extern "C" void kernel_launch(void* const* d_in, const int* in_sizes, int n_in,
                              void* d_out, int out_size, void* d_ws, size_t ws_size,
                              hipStream_t stream) {
    (void)in_sizes; (void)n_in; (void)out_size; (void)ws_size;
    const float* x = (const float*)d_in[0];
    float* out = (float*)d_out;

    float* magmax = (float*)d_ws;                  // 32 floats (atomicMax target)
    float2* rf2 = (float2*)((char*)d_ws + 16384);  // [B][WR][H] float2 = 134.5 MB

    hipMemsetAsync(d_ws, 0, 16384, stream);
    row_fft_kernel<<<BATCH * 128, 256, 0, stream>>>(x, rf2);
    col_fft_kernel<<<(BATCH * WR) / 2, 128, 0, stream>>>(rf2, magmax);
    dim3 gridC(57, BATCH);
    stats_kernel<<<gridC, 256, 0, stream>>>((float*)rf2);
    finalize_kernel<<<BATCH, 64, 0, stream>>>((const float*)rf2, magmax, out);
}

// Round 2
// 520.329 us; speedup vs baseline: 1.1518x; 1.1518x over previous
//
#include <hip/hip_runtime.h>
#include <math.h>

#define BATCH 32
#define HH 1024
#define WW 1024
#define WR 513
#define NPIX (HH * WR)
#define TWO_PI_F 6.28318530717958647692f

// Same-wave LDS fence: each wave only touches its own LDS region, so a full
// block barrier is unnecessary — wait for this wave's own LDS ops instead.
#define LGKM_SYNC() __asm__ __volatile__("s_waitcnt lgkmcnt(0)" ::: "memory")

__device__ __forceinline__ float2 cadd(float2 a, float2 b) { return make_float2(a.x + b.x, a.y + b.y); }
__device__ __forceinline__ float2 csub(float2 a, float2 b) { return make_float2(a.x - b.x, a.y - b.y); }
__device__ __forceinline__ float2 cmul(float2 a, float2 b) {
    return make_float2(a.x * b.x - a.y * b.y, a.x * b.y + a.y * b.x);
}

// atan2 via odd minimax poly on [0,1] (max err ~1e-5 rad) + quadrant fixup.
__device__ __forceinline__ float fast_atan2f(float y, float x) {
    float ax = __builtin_fabsf(x), ay = __builtin_fabsf(y);
    float mx = fmaxf(ax, ay), mn = fminf(ax, ay);
    float a = mn * __builtin_amdgcn_rcpf(mx);
    float s = a * a;
    float r = fmaf(fmaf(fmaf(fmaf(0.0208351f, s, -0.085133f), s, 0.180141f),
                        s, -0.3302995f), s, 0.999866f) * a;
    if (ay > ax) r = 1.5707963268f - r;
    if (x < 0.0f) r = 3.1415926536f - r;
    return (y < 0.0f) ? -r : r;
}

// Register-renaming permutation of the in-place DIF FFT16 output:
// after fft16_ip, slot[ridx(k)] holds X[k]. ridx is an involution
// (2-bit digit swap), compile-time only — zero instructions.
__device__ __forceinline__ constexpr int ridx(int k) { return ((k & 3) << 2) | (k >> 2); }

// In-place radix-4 DIF 16-point FFT. Natural-order input d[0..15];
// output digit-reversed: d[4r+m] = X[4m+r] (i.e. d[ridx(k)] = X[k]).
// No b[16] double buffer -> ~32 fewer live VGPRs than the out-of-place form.
__device__ __forceinline__ void fft16_ip(float2* d) {
    const float2 Wt1[4] = {{1.f, 0.f},
                           {0.92387953f, -0.38268343f},
                           {0.70710678f, -0.70710678f},
                           {0.38268343f, -0.92387953f}};
    const float2 Wt2[4] = {{1.f, 0.f},
                           {0.70710678f, -0.70710678f},
                           {0.f, -1.f},
                           {-0.70710678f, -0.70710678f}};
    const float2 Wt3[4] = {{1.f, 0.f},
                           {0.38268343f, -0.92387953f},
                           {-0.70710678f, -0.70710678f},
                           {-0.92387953f, 0.38268343f}};
#pragma unroll
    for (int t = 0; t < 4; ++t) {
        float2 x0 = d[t], x1 = d[t + 4], x2 = d[t + 8], x3 = d[t + 12];
        float2 a0 = cadd(x0, x2), a1 = csub(x0, x2), a2 = cadd(x1, x3), a3 = csub(x1, x3);
        d[t]      = cadd(a0, a2);
        d[t + 4]  = cmul(make_float2(a1.x + a3.y, a1.y - a3.x), Wt1[t]);
        d[t + 8]  = cmul(csub(a0, a2), Wt2[t]);
        d[t + 12] = cmul(make_float2(a1.x - a3.y, a1.y + a3.x), Wt3[t]);
    }
#pragma unroll
    for (int r = 0; r < 4; ++r) {
        float2 x0 = d[4 * r], x1 = d[4 * r + 1], x2 = d[4 * r + 2], x3 = d[4 * r + 3];
        float2 e0 = cadd(x0, x2), e1 = csub(x0, x2), e2 = cadd(x1, x3), e3 = csub(x1, x3);
        d[4 * r]     = cadd(e0, e2);
        d[4 * r + 1] = make_float2(e1.x + e3.y, e1.y - e3.x);
        d[4 * r + 2] = csub(e0, e2);
        d[4 * r + 3] = make_float2(e1.x - e3.y, e1.y + e3.x);
    }
}

// Wave-level 1024-pt FFT. Input: v[j] = x[lane + 64*j]. sb = this wave's
// PRIVATE 1024-float2 (8 KB) LDS scratch. No block barriers.
// Single-pass float2 transpose with XOR bank swizzle (col ^ k2): write and
// read phases both land 4 accesses per bank-pair = the wave64-b64 minimum.
// Output: v[ridx(m)] = X[(lane&15) + 16*m + 256*kq], kq = 2*((lane>>4)&1) + ((lane>>5)&1).
__device__ __forceinline__ void wave_fft1024(float2* v, float2* sb, int lane) {
    fft16_ip(v);                      // v[ridx(k2)] = V[k2]
    float s, c;
    __sincosf(-TWO_PI_F * (float)lane * (1.0f / 1024.0f), &s, &c);
    float2 T = make_float2(c, s), w = T;
#pragma unroll
    for (int k2 = 1; k2 < 16; ++k2) { v[ridx(k2)] = cmul(v[ridx(k2)], w); w = cmul(w, T); }
    // 16x64 transpose, one float2 pass, XOR-swizzled columns.
    const int k2p = lane & 15, qp = lane >> 4;
#pragma unroll
    for (int k2 = 0; k2 < 16; ++k2) sb[(k2 << 6) | (lane ^ k2)] = v[ridx(k2)];
    LGKM_SYNC();
#pragma unroll
    for (int m = 0; m < 16; ++m) v[m] = sb[(k2p << 6) | ((4 * m + qp) ^ k2p)];
    LGKM_SYNC();                      // scratch reusable by caller after return
    fft16_ip(v);                      // v[ridx(km)] = Y[km]
    __sincosf(-TWO_PI_F * (float)qp * (1.0f / 64.0f), &s, &c);
    float2 U = make_float2(c, s);
    w = U;
#pragma unroll
    for (int km = 1; km < 16; ++km) { v[ridx(km)] = cmul(v[ridx(km)], w); w = cmul(w, U); }
    const bool hi2 = (lane & 32) != 0, hi1 = (lane & 16) != 0;
#pragma unroll
    for (int m = 0; m < 16; ++m) {   // slot-wise: any order
        float2 a = v[m];
        float2 o = make_float2(__shfl_xor(a.x, 32, 64), __shfl_xor(a.y, 32, 64));
        float2 s1 = hi2 ? csub(o, a) : cadd(a, o);
        if (hi2 && hi1) s1 = make_float2(s1.y, -s1.x);
        float2 o2 = make_float2(__shfl_xor(s1.x, 16, 64), __shfl_xor(s1.y, 16, 64));
        v[m] = hi1 ? csub(o2, s1) : cadd(s1, o2);
    }
}

// ---------------------------------------------------------------------------
// Kernel A: 4 waves/block, each wave = 2 packed real rows -> 1 complex FFT.
// One block barrier total. LDS now 32 KB/block -> 5 blocks/CU (was 4).
// ---------------------------------------------------------------------------
__global__ __launch_bounds__(256, 4) void row_fft_kernel(const float* __restrict__ x,
                                                         float2* __restrict__ rf2) {
    __shared__ float2 buf[4][1024];
    const int t = threadIdx.x, w = t >> 6, lane = t & 63;
    const int b = blockIdx.x >> 7;
    const int h0 = (blockIdx.x & 127) * 8;
    const float* r0 = x + ((long long)b * HH + h0 + 2 * w) * (long long)WW;
    const float* r1 = r0 + WW;
    float2 v[16];
#pragma unroll
    for (int j = 0; j < 16; ++j) v[j] = make_float2(r0[lane + 64 * j], r1[lane + 64 * j]);
    float2* mybuf = &buf[w][0];
    wave_fft1024(v, mybuf, lane);
    const int kq = 2 * ((lane >> 4) & 1) + ((lane >> 5) & 1);
    const int kbase = (lane & 15) + 256 * kq;
#pragma unroll
    for (int m = 0; m < 16; ++m) mybuf[kbase + 16 * m] = v[ridx(m)];
    __syncthreads();
    for (int idx = t; idx < 513 * 8; idx += 256) {
        int k = idx >> 3, j = idx & 7, p = j >> 1, which = j & 1;
        float2 zk = buf[p][k];
        float2 zn = buf[p][(1024 - k) & 1023];
        float2 val = which ? make_float2(0.5f * (zk.y + zn.y), 0.5f * (zn.x - zk.x))
                           : make_float2(0.5f * (zk.x + zn.x), 0.5f * (zk.y - zn.y));
        rf2[((long long)b * WR + k) * 1024 + h0 + j] = val;
    }
}

// ---------------------------------------------------------------------------
// Kernel B: 2 waves/block, each wave = one contiguous 8KB row FFT of rf2[b][k][:].
// Barrier-free; 16 KB LDS/block. launch_bounds(128,4): round-1 showed that
// forcing 8 waves/EU makes the compiler spill (VGPR 32, +590 MB scratch
// traffic, 168->238 us). Instead the fft16_ip + single-pass-float2-transpose
// register diet lowers natural VGPR below 64 so HW occupancy rises by itself.
// ---------------------------------------------------------------------------
__global__ __launch_bounds__(128, 4) void col_fft_kernel(float2* __restrict__ rf2,
                                                         float* __restrict__ magmax) {
    __shared__ float2 sb[2][1024];
    const int t = threadIdx.x, w = t >> 6, lane = t & 63;
    const int fid = blockIdx.x * 2 + w;
    const int b = fid / WR, k = fid - b * WR;
    float2* row = rf2 + ((long long)b * WR + k) * 1024;
    float2 v[16];
#pragma unroll
    for (int j = 0; j < 16; ++j) v[j] = row[lane + 64 * j];
    wave_fft1024(v, &sb[w][0], lane);
    float* pu = (float*)row;
    const int kq = 2 * ((lane >> 4) & 1) + ((lane >> 5) & 1);
    const int hbase = (lane & 15) + 256 * kq;
    float mmax = 0.0f;
#pragma unroll
    for (int m = 0; m < 16; ++m) {
        float2 z = v[ridx(m)];
        mmax = fmaxf(mmax, __builtin_amdgcn_sqrtf(z.x * z.x + z.y * z.y));
        float ph = fast_atan2f(z.y, z.x);
        pu[hbase + 16 * m] = (ph < 0.0f) ? ph + TWO_PI_F : ph;
    }
#pragma unroll
    for (int off = 32; off; off >>= 1) mmax = fmaxf(mmax, __shfl_down(mmax, off));
    if (lane == 0) atomicMax((int*)(magmax + b), __float_as_int(mmax));
}

// ---------------------------------------------------------------------------
// Kernel C: single-pass gradients + all 55 Zernike moments + mask count.
// No atomics: wave shuffle-reduce -> LDS -> per-block 60-float partial into
// the dead upper half of pu row (b*57 + blockIdx.x).
// (256,2): reverted — round-1's (256,3) was neutral-to-negative.
// ---------------------------------------------------------------------------
#define WRED(var, idx)                                                     \
    {                                                                      \
        float r_ = var;                                                    \
        _Pragma("unroll")                                                  \
        for (int off_ = 32; off_; off_ >>= 1) r_ += __shfl_down(r_, off_); \
        if (lane == 0) red[wv * 64 + (idx)] = r_;                          \
    }

__global__ __launch_bounds__(256, 2) void stats_kernel(float* __restrict__ pu) {
    __shared__ float red[4 * 64];
    const int b = blockIdx.y;
    const int k0 = blockIdx.x * 9;
    const float* base = pu + (long long)b * WR * 2048;
    float a00 = 0.f, a11 = 0.f, a20 = 0.f, a22 = 0.f, a31 = 0.f, a33 = 0.f,
          a40 = 0.f, a42 = 0.f, a44 = 0.f, a51 = 0.f, a53 = 0.f, a55 = 0.f,
          a60 = 0.f, a62 = 0.f, a64 = 0.f, a66 = 0.f, a71 = 0.f, a73 = 0.f,
          a75 = 0.f, a77 = 0.f, a80 = 0.f, a82 = 0.f, a84 = 0.f, a86 = 0.f,
          a88 = 0.f, a91 = 0.f, a93 = 0.f, a95 = 0.f, a97 = 0.f, a99 = 0.f;
    float b11 = 0.f, b22 = 0.f, b31 = 0.f, b33 = 0.f, b42 = 0.f, b44 = 0.f,
          b51 = 0.f, b53 = 0.f, b55 = 0.f, b62 = 0.f, b64 = 0.f, b66 = 0.f,
          b71 = 0.f, b73 = 0.f, b75 = 0.f, b77 = 0.f, b82 = 0.f, b84 = 0.f,
          b86 = 0.f, b88 = 0.f, b91 = 0.f, b93 = 0.f, b95 = 0.f, b97 = 0.f,
          b99 = 0.f;
    float sgx = 0.f, sgx2 = 0.f, sgy = 0.f, sgy2 = 0.f, cnt = 0.f;

    for (int kk = 0; kk < 9; ++kk) {
        const int k = k0 + kk;
        const float* rowc = base + (long long)k * 2048;
        const float* rowm = rowc - 2048;
        const float* rowp = rowc + 2048;
        const float xv = -1.0f + (1.0f / 256.0f) * (float)k;
        const float xv2 = xv * xv;
        for (int h = threadIdx.x; h < 1024; h += 256) {
            float v = rowc[h];
            float gx, gy;
            if (k == 0)            gx = rowp[h] - v;
            else if (k == WR - 1)  gx = v - rowm[h];
            else                   gx = 0.5f * (rowp[h] - rowm[h]);
            if (h == 0)            gy = rowc[1] - v;
            else if (h == 1023)    gy = v - rowc[1022];
            else                   gy = 0.5f * (rowc[h + 1] - rowc[h - 1]);
            sgx += gx; sgx2 += gx * gx; sgy += gy; sgy2 += gy * gy;

            const float yv = -1.0f + (2.0f / 1023.0f) * (float)h;
            const float r2 = xv2 + yv * yv;
            if (r2 <= 1.0f) {
                cnt += 1.0f;
                const float rho = sqrtf(r2);
                const float inv = rsqrtf(r2);
                const float c1 = xv * inv;
                const float s1 = yv * inv;
                const float c2 = 2.f * c1 * c1 - 1.f;
                const float c3 = 2.f * c1 * c2 - c1;
                const float c4 = 2.f * c1 * c3 - c2;
                const float c5 = 2.f * c1 * c4 - c3;
                const float c6 = 2.f * c1 * c5 - c4;
                const float c7 = 2.f * c1 * c6 - c5;
                const float c8 = 2.f * c1 * c7 - c6;
                const float c9 = 2.f * c1 * c8 - c7;
                const float s2 = 2.f * c1 * s1;
                const float s3 = 2.f * c1 * s2 - s1;
                const float s4 = 2.f * c1 * s3 - s2;
                const float s5 = 2.f * c1 * s4 - s3;
                const float s6 = 2.f * c1 * s5 - s4;
                const float s7 = 2.f * c1 * s6 - s5;
                const float s8 = 2.f * c1 * s7 - s6;
                const float s9 = 2.f * c1 * s8 - s7;
                const float w0 = v,        w1 = w0 * rho, w2 = w1 * rho, w3 = w2 * rho,
                            w4 = w3 * rho, w5 = w4 * rho, w6 = w5 * rho, w7 = w6 * rho,
                            w8 = w7 * rho, w9 = w8 * rho;
                a00 += w0;
                a11 += w1 * c1;
                a20 += w2;      a22 += w2 * c2;
                a31 += w3 * c1; a33 += w3 * c3;
                a40 += w4;      a42 += w4 * c2; a44 += w4 * c4;
                a51 += w5 * c1; a53 += w5 * c3; a55 += w5 * c5;
                a60 += w6;      a62 += w6 * c2; a64 += w6 * c4; a66 += w6 * c6;
                a71 += w7 * c1; a73 += w7 * c3; a75 += w7 * c5; a77 += w7 * c7;
                a80 += w8;      a82 += w8 * c2; a84 += w8 * c4; a86 += w8 * c6; a88 += w8 * c8;
                a91 += w9 * c1; a93 += w9 * c3; a95 += w9 * c5; a97 += w9 * c7; a99 += w9 * c9;
                b11 += w1 * s1;
                b22 += w2 * s2;
                b31 += w3 * s1; b33 += w3 * s3;
                b42 += w4 * s2; b44 += w4 * s4;
                b51 += w5 * s1; b53 += w5 * s3; b55 += w5 * s5;
                b62 += w6 * s2; b64 += w6 * s4; b66 += w6 * s6;
                b71 += w7 * s1; b73 += w7 * s3; b75 += w7 * s5; b77 += w7 * s7;
                b82 += w8 * s2; b84 += w8 * s4; b86 += w8 * s6; b88 += w8 * s8;
                b91 += w9 * s1; b93 += w9 * s3; b95 += w9 * s5; b97 += w9 * s7; b99 += w9 * s9;
            }
        }
    }

    const int wv = threadIdx.x >> 6, lane = threadIdx.x & 63;
    WRED(a00, 0);  WRED(a11, 1);  WRED(a20, 2);  WRED(a22, 3);  WRED(a31, 4);
    WRED(a33, 5);  WRED(a40, 6);  WRED(a42, 7);  WRED(a44, 8);  WRED(a51, 9);
    WRED(a53, 10); WRED(a55, 11); WRED(a60, 12); WRED(a62, 13); WRED(a64, 14);
    WRED(a66, 15); WRED(a71, 16); WRED(a73, 17); WRED(a75, 18); WRED(a77, 19);
    WRED(a80, 20); WRED(a82, 21); WRED(a84, 22); WRED(a86, 23); WRED(a88, 24);
    WRED(a91, 25); WRED(a93, 26); WRED(a95, 27); WRED(a97, 28); WRED(a99, 29);
    WRED(b11, 30); WRED(b22, 31); WRED(b31, 32); WRED(b33, 33); WRED(b42, 34);
    WRED(b44, 35); WRED(b51, 36); WRED(b53, 37); WRED(b55, 38); WRED(b62, 39);
    WRED(b64, 40); WRED(b66, 41); WRED(b71, 42); WRED(b73, 43); WRED(b75, 44);
    WRED(b77, 45); WRED(b82, 46); WRED(b84, 47); WRED(b86, 48); WRED(b88, 49);
    WRED(b91, 50); WRED(b93, 51); WRED(b95, 52); WRED(b97, 53); WRED(b99, 54);
    WRED(sgx, 55); WRED(sgx2, 56); WRED(sgy, 57); WRED(sgy2, 58); WRED(cnt, 59);
    __syncthreads();
    const int t = threadIdx.x;
    if (t < 60) {
        float s = red[t] + red[64 + t] + red[128 + t] + red[192 + t];
        pu[((long long)(b * 57 + blockIdx.x)) * 2048 + 1024 + t] = s;
    }
}

// ---------------------------------------------------------------------------
// Kernel D: sum 57 block-partials per batch, map moments -> Zernike coeffs,
// finalize stats.
// ---------------------------------------------------------------------------
__device__ int moment_index(int p, int a, int is_cos) {
    int ai = 0;
    for (int pp = 0; pp < 10; ++pp)
        for (int aa = (pp & 1); aa <= pp; aa += 2) {
            if (is_cos && pp == p && aa == a) return ai;
            ++ai;
        }
    for (int pp = 1; pp < 10; ++pp)
        for (int aa = ((pp & 1) ? 1 : 2); aa <= pp; aa += 2) {
            if (!is_cos && pp == p && aa == a) return ai;
            ++ai;
        }
    return 0;
}

__device__ float factf(int n) {
    float f = 1.0f;
    for (int i = 2; i <= n; ++i) f *= (float)i;
    return f;
}

__global__ void finalize_kernel(const float* __restrict__ pu,
                                const float* __restrict__ magmax,
                                float* __restrict__ out) {
    __shared__ float abf[64];
    const int b = blockIdx.x;
    const int j = threadIdx.x;
    if (j < 60) {
        float s = 0.0f;
        for (int i = 0; i < 57; ++i)
            s += pu[((long long)(b * 57 + i)) * 2048 + 1024 + j];
        abf[j] = s;
    }
    __syncthreads();
    if (j >= 60) return;
    const float NF = (float)NPIX;
    float val;
    if (j < 55) {
        int tt = j, n = 0;
        while (tt >= n + 1) { tt -= (n + 1); ++n; }
        int m = -n + 2 * tt;
        int am = m < 0 ? -m : m;
        float s = 0.0f;
        for (int k = 0; k <= (n - am) / 2; ++k) {
            float c = factf(n - k) /
                      (factf(k) * factf((n + am) / 2 - k) * factf((n - am) / 2 - k));
            if (k & 1) c = -c;
            int p = n - 2 * k;
            s += c * abf[moment_index(p, am, m >= 0 ? 1 : 0)];
        }
        val = s / abf[59];
    } else if (j == 55) {
        val = abf[55] / NF;
    } else if (j == 56) {
        val = abf[57] / NF;
    } else if (j == 57) {
        float sum = abf[55], sq = abf[56];
        val = sqrtf(fmaxf(0.0f, (sq - sum * sum / NF) / (NF - 1.0f)));
    } else if (j == 58) {
        float sum = abf[57], sq = abf[58];
        val = sqrtf(fmaxf(0.0f, (sq - sum * sum / NF) / (NF - 1.0f)));
    } else {
        val = magmax[b];
    }
    out[b * 60 + j] = val;
}

// ---------------------------------------------------------------------------
extern "C" void kernel_launch(void* const* d_in, const int* in_sizes, int n_in,
                              void* d_out, int out_size, void* d_ws, size_t ws_size,
                              hipStream_t stream) {
    (void)in_sizes; (void)n_in; (void)out_size; (void)ws_size;
    const float* x = (const float*)d_in[0];
    float* out = (float*)d_out;

    float* magmax = (float*)d_ws;                  // 32 floats (atomicMax target)
    float2* rf2 = (float2*)((char*)d_ws + 16384);  // [B][WR][H] float2 = 134.5 MB

    hipMemsetAsync(d_ws, 0, 16384, stream);
    row_fft_kernel<<<BATCH * 128, 256, 0, stream>>>(x, rf2);
    col_fft_kernel<<<(BATCH * WR) / 2, 128, 0, stream>>>(rf2, magmax);
    dim3 gridC(57, BATCH);
    stats_kernel<<<gridC, 256, 0, stream>>>((float*)rf2);
    finalize_kernel<<<BATCH, 64, 0, stream>>>((const float*)rf2, magmax, out);
}

// Round 3
// 517.972 us; speedup vs baseline: 1.1571x; 1.0046x over previous
//
#include <hip/hip_runtime.h>
#include <math.h>

#define BATCH 32
#define HH 1024
#define WW 1024
#define WR 513
#define NPIX (HH * WR)
#define TWO_PI_F 6.28318530717958647692f

// Same-wave LDS fence: each wave only touches its own LDS region, so a full
// block barrier is unnecessary — wait for this wave's own LDS ops instead.
#define LGKM_SYNC() __asm__ __volatile__("s_waitcnt lgkmcnt(0)" ::: "memory")

__device__ __forceinline__ float2 cadd(float2 a, float2 b) { return make_float2(a.x + b.x, a.y + b.y); }
__device__ __forceinline__ float2 csub(float2 a, float2 b) { return make_float2(a.x - b.x, a.y - b.y); }
__device__ __forceinline__ float2 cmul(float2 a, float2 b) {
    return make_float2(a.x * b.x - a.y * b.y, a.x * b.y + a.y * b.x);
}

// atan2 via odd minimax poly on [0,1] (max err ~1e-5 rad) + quadrant fixup.
__device__ __forceinline__ float fast_atan2f(float y, float x) {
    float ax = __builtin_fabsf(x), ay = __builtin_fabsf(y);
    float mx = fmaxf(ax, ay), mn = fminf(ax, ay);
    float a = mn * __builtin_amdgcn_rcpf(mx);
    float s = a * a;
    float r = fmaf(fmaf(fmaf(fmaf(0.0208351f, s, -0.085133f), s, 0.180141f),
                        s, -0.3302995f), s, 0.999866f) * a;
    if (ay > ax) r = 1.5707963268f - r;
    if (x < 0.0f) r = 3.1415926536f - r;
    return (y < 0.0f) ? -r : r;
}

// Register-renaming permutation of the in-place DIF FFT16 output:
// after fft16_ip, slot[ridx(k)] holds X[k]. ridx is an involution
// (2-bit digit swap), compile-time only — zero instructions.
__device__ __forceinline__ constexpr int ridx(int k) { return ((k & 3) << 2) | (k >> 2); }

// In-place radix-4 DIF 16-point FFT. Natural-order input d[0..15];
// output digit-reversed: d[ridx(k)] = X[k].
__device__ __forceinline__ void fft16_ip(float2* d) {
    const float2 Wt1[4] = {{1.f, 0.f},
                           {0.92387953f, -0.38268343f},
                           {0.70710678f, -0.70710678f},
                           {0.38268343f, -0.92387953f}};
    const float2 Wt2[4] = {{1.f, 0.f},
                           {0.70710678f, -0.70710678f},
                           {0.f, -1.f},
                           {-0.70710678f, -0.70710678f}};
    const float2 Wt3[4] = {{1.f, 0.f},
                           {0.38268343f, -0.92387953f},
                           {-0.70710678f, -0.70710678f},
                           {-0.92387953f, 0.38268343f}};
#pragma unroll
    for (int t = 0; t < 4; ++t) {
        float2 x0 = d[t], x1 = d[t + 4], x2 = d[t + 8], x3 = d[t + 12];
        float2 a0 = cadd(x0, x2), a1 = csub(x0, x2), a2 = cadd(x1, x3), a3 = csub(x1, x3);
        d[t]      = cadd(a0, a2);
        d[t + 4]  = cmul(make_float2(a1.x + a3.y, a1.y - a3.x), Wt1[t]);
        d[t + 8]  = cmul(csub(a0, a2), Wt2[t]);
        d[t + 12] = cmul(make_float2(a1.x - a3.y, a1.y + a3.x), Wt3[t]);
    }
#pragma unroll
    for (int r = 0; r < 4; ++r) {
        float2 x0 = d[4 * r], x1 = d[4 * r + 1], x2 = d[4 * r + 2], x3 = d[4 * r + 3];
        float2 e0 = cadd(x0, x2), e1 = csub(x0, x2), e2 = cadd(x1, x3), e3 = csub(x1, x3);
        d[4 * r]     = cadd(e0, e2);
        d[4 * r + 1] = make_float2(e1.x + e3.y, e1.y - e3.x);
        d[4 * r + 2] = csub(e0, e2);
        d[4 * r + 3] = make_float2(e1.x - e3.y, e1.y + e3.x);
    }
}

// Log-depth (4) twiddle power tree: Wt[k] = T^k, k=1..15. Replaces the
// 15-step serial cmul chain (depth 15 -> 4) on the latency-critical path.
__device__ __forceinline__ void twiddle_tree(float2 T, float2* Wt) {
    Wt[1] = T;
    Wt[2] = cmul(T, T);
    Wt[3] = cmul(Wt[2], T);
    Wt[4] = cmul(Wt[2], Wt[2]);
    Wt[5] = cmul(Wt[4], Wt[1]);
    Wt[6] = cmul(Wt[4], Wt[2]);
    Wt[7] = cmul(Wt[4], Wt[3]);
    Wt[8] = cmul(Wt[4], Wt[4]);
    Wt[9]  = cmul(Wt[8], Wt[1]);
    Wt[10] = cmul(Wt[8], Wt[2]);
    Wt[11] = cmul(Wt[8], Wt[3]);
    Wt[12] = cmul(Wt[8], Wt[4]);
    Wt[13] = cmul(Wt[8], Wt[5]);
    Wt[14] = cmul(Wt[8], Wt[6]);
    Wt[15] = cmul(Wt[8], Wt[7]);
}

// Wave-level 1024-pt FFT (single row — used by row_fft_kernel).
// Output: v[ridx(m)] = X[(lane&15) + 16*m + 256*kq], kq = 2*((lane>>4)&1) + ((lane>>5)&1).
__device__ __forceinline__ void wave_fft1024(float2* v, float2* sb, int lane) {
    fft16_ip(v);                      // v[ridx(k2)] = V[k2]
    float s, c;
    __sincosf(-TWO_PI_F * (float)lane * (1.0f / 1024.0f), &s, &c);
    float2 Wt[16];
    twiddle_tree(make_float2(c, s), Wt);
#pragma unroll
    for (int k2 = 1; k2 < 16; ++k2) v[ridx(k2)] = cmul(v[ridx(k2)], Wt[k2]);
    // 16x64 transpose, one float2 pass, XOR-swizzled columns.
    const int k2p = lane & 15, qp = lane >> 4;
#pragma unroll
    for (int k2 = 0; k2 < 16; ++k2) sb[(k2 << 6) | (lane ^ k2)] = v[ridx(k2)];
    LGKM_SYNC();
#pragma unroll
    for (int m = 0; m < 16; ++m) v[m] = sb[(k2p << 6) | ((4 * m + qp) ^ k2p)];
    LGKM_SYNC();                      // scratch reusable by caller after return
    fft16_ip(v);                      // v[ridx(km)] = Y[km]
    __sincosf(-TWO_PI_F * (float)qp * (1.0f / 64.0f), &s, &c);
    twiddle_tree(make_float2(c, s), Wt);
#pragma unroll
    for (int km = 1; km < 16; ++km) v[ridx(km)] = cmul(v[ridx(km)], Wt[km]);
    const bool hi2 = (lane & 32) != 0, hi1 = (lane & 16) != 0;
#pragma unroll
    for (int m = 0; m < 16; ++m) {   // slot-wise: any order
        float2 a = v[m];
        float2 o = make_float2(__shfl_xor(a.x, 32, 64), __shfl_xor(a.y, 32, 64));
        float2 s1 = hi2 ? csub(o, a) : cadd(a, o);
        if (hi2 && hi1) s1 = make_float2(s1.y, -s1.x);
        float2 o2 = make_float2(__shfl_xor(s1.x, 16, 64), __shfl_xor(s1.y, 16, 64));
        v[m] = hi1 ? csub(o2, s1) : cadd(s1, o2);
    }
}

// ---------------------------------------------------------------------------
// Kernel A: 4 waves/block, each wave = 2 packed real rows -> 1 complex FFT.
// One block barrier total. (unchanged round-2 structure — it measured faster)
// ---------------------------------------------------------------------------
__global__ __launch_bounds__(256, 4) void row_fft_kernel(const float* __restrict__ x,
                                                         float2* __restrict__ rf2) {
    __shared__ float2 buf[4][1024];
    const int t = threadIdx.x, w = t >> 6, lane = t & 63;
    const int b = blockIdx.x >> 7;
    const int h0 = (blockIdx.x & 127) * 8;
    const float* r0 = x + ((long long)b * HH + h0 + 2 * w) * (long long)WW;
    const float* r1 = r0 + WW;
    float2 v[16];
#pragma unroll
    for (int j = 0; j < 16; ++j) v[j] = make_float2(r0[lane + 64 * j], r1[lane + 64 * j]);
    float2* mybuf = &buf[w][0];
    wave_fft1024(v, mybuf, lane);
    const int kq = 2 * ((lane >> 4) & 1) + ((lane >> 5) & 1);
    const int kbase = (lane & 15) + 256 * kq;
#pragma unroll
    for (int m = 0; m < 16; ++m) mybuf[kbase + 16 * m] = v[ridx(m)];
    __syncthreads();
    for (int idx = t; idx < 513 * 8; idx += 256) {
        int k = idx >> 3, j = idx & 7, p = j >> 1, which = j & 1;
        float2 zk = buf[p][k];
        float2 zn = buf[p][(1024 - k) & 1023];
        float2 val = which ? make_float2(0.5f * (zk.y + zn.y), 0.5f * (zn.x - zk.x))
                           : make_float2(0.5f * (zk.x + zn.x), 0.5f * (zk.y - zn.y));
        rf2[((long long)b * WR + k) * 1024 + h0 + j] = val;
    }
}

// ---------------------------------------------------------------------------
// Kernel B: DUAL-ROW col FFT. Each wave processes TWO independent 1024-pt
// rows in interleaved register streams: every dependency-chain stall of row A
// is filled by row B's instructions (ILP, not TLP — rounds 0-2 showed the
// occupancy route is capped/spilly). Twiddles depend only on lane -> computed
// ONCE (log-depth tree) and shared by both rows. Transpose: proven
// conflict-free two-pass b32 stride-68, dual-region so both rows share each
// lgkmcnt fence (3 fences for 2 rows vs 4 per row originally).
// LDS 17408 B/block; launch_bounds(128,2) -> VGPR cap 128, est ~110 natural.
// ---------------------------------------------------------------------------
__global__ __launch_bounds__(128, 2) void col_fft_kernel(float2* __restrict__ rf2,
                                                         float* __restrict__ magmax) {
    __shared__ float sb[2][2][1088];
    const int t = threadIdx.x, w = t >> 6, lane = t & 63;
    const int fid0 = blockIdx.x * 4 + w * 2;
    const int fid1 = fid0 + 1;
    const int b0 = fid0 / WR, k0 = fid0 - b0 * WR;
    const int b1 = fid1 / WR, k1 = fid1 - b1 * WR;
    float2* rowA = rf2 + ((long long)b0 * WR + k0) * 1024;
    float2* rowB = rf2 + ((long long)b1 * WR + k1) * 1024;
    float2 va[16], vb[16];
#pragma unroll
    for (int j = 0; j < 16; ++j) va[j] = rowA[lane + 64 * j];
#pragma unroll
    for (int j = 0; j < 16; ++j) vb[j] = rowB[lane + 64 * j];

    fft16_ip(va);
    fft16_ip(vb);
    float s, c;
    __sincosf(-TWO_PI_F * (float)lane * (1.0f / 1024.0f), &s, &c);
    {
        float2 Wt[16];
        twiddle_tree(make_float2(c, s), Wt);
#pragma unroll
        for (int k2 = 1; k2 < 16; ++k2) {
            va[ridx(k2)] = cmul(va[ridx(k2)], Wt[k2]);
            vb[ridx(k2)] = cmul(vb[ridx(k2)], Wt[k2]);
        }
    }
    // Dual-region two-pass b32 transpose (stride 68 = conflict-free).
    const int k2p = lane & 15, qp = lane >> 4;
    float* sA = &sb[w][0][0];
    float* sB = &sb[w][1][0];
    float txA[16], txB[16];
#pragma unroll
    for (int k2 = 0; k2 < 16; ++k2) {
        sA[68 * k2 + lane] = va[ridx(k2)].x;
        sB[68 * k2 + lane] = vb[ridx(k2)].x;
    }
    LGKM_SYNC();
#pragma unroll
    for (int m = 0; m < 16; ++m) {
        txA[m] = sA[68 * k2p + 4 * m + qp];
        txB[m] = sB[68 * k2p + 4 * m + qp];
    }
    LGKM_SYNC();   // all cross-lane reads done before overwrite (.y pass)
#pragma unroll
    for (int k2 = 0; k2 < 16; ++k2) {
        sA[68 * k2 + lane] = va[ridx(k2)].y;
        sB[68 * k2 + lane] = vb[ridx(k2)].y;
    }
    LGKM_SYNC();
#pragma unroll
    for (int m = 0; m < 16; ++m) {
        va[m] = make_float2(txA[m], sA[68 * k2p + 4 * m + qp]);
        vb[m] = make_float2(txB[m], sB[68 * k2p + 4 * m + qp]);
    }

    fft16_ip(va);
    fft16_ip(vb);
    __sincosf(-TWO_PI_F * (float)qp * (1.0f / 64.0f), &s, &c);
    {
        float2 Wt[16];
        twiddle_tree(make_float2(c, s), Wt);
#pragma unroll
        for (int km = 1; km < 16; ++km) {
            va[ridx(km)] = cmul(va[ridx(km)], Wt[km]);
            vb[ridx(km)] = cmul(vb[ridx(km)], Wt[km]);
        }
    }
    const bool hi2 = (lane & 32) != 0, hi1 = (lane & 16) != 0;
#pragma unroll
    for (int m = 0; m < 16; ++m) {
        {
            float2 a = va[m];
            float2 o = make_float2(__shfl_xor(a.x, 32, 64), __shfl_xor(a.y, 32, 64));
            float2 s1 = hi2 ? csub(o, a) : cadd(a, o);
            if (hi2 && hi1) s1 = make_float2(s1.y, -s1.x);
            float2 o2 = make_float2(__shfl_xor(s1.x, 16, 64), __shfl_xor(s1.y, 16, 64));
            va[m] = hi1 ? csub(o2, s1) : cadd(s1, o2);
        }
        {
            float2 a = vb[m];
            float2 o = make_float2(__shfl_xor(a.x, 32, 64), __shfl_xor(a.y, 32, 64));
            float2 s1 = hi2 ? csub(o, a) : cadd(a, o);
            if (hi2 && hi1) s1 = make_float2(s1.y, -s1.x);
            float2 o2 = make_float2(__shfl_xor(s1.x, 16, 64), __shfl_xor(s1.y, 16, 64));
            vb[m] = hi1 ? csub(o2, s1) : cadd(s1, o2);
        }
    }
    float* puA = (float*)rowA;
    float* puB = (float*)rowB;
    const int kq = 2 * ((lane >> 4) & 1) + ((lane >> 5) & 1);
    const int hbase = (lane & 15) + 256 * kq;
    float mA = 0.0f, mB = 0.0f;
#pragma unroll
    for (int m = 0; m < 16; ++m) {
        float2 zA = va[ridx(m)];
        float2 zB = vb[ridx(m)];
        mA = fmaxf(mA, __builtin_amdgcn_sqrtf(zA.x * zA.x + zA.y * zA.y));
        mB = fmaxf(mB, __builtin_amdgcn_sqrtf(zB.x * zB.x + zB.y * zB.y));
        float phA = fast_atan2f(zA.y, zA.x);
        float phB = fast_atan2f(zB.y, zB.x);
        puA[hbase + 16 * m] = (phA < 0.0f) ? phA + TWO_PI_F : phA;
        puB[hbase + 16 * m] = (phB < 0.0f) ? phB + TWO_PI_F : phB;
    }
#pragma unroll
    for (int off = 32; off; off >>= 1) {
        mA = fmaxf(mA, __shfl_down(mA, off));
        mB = fmaxf(mB, __shfl_down(mB, off));
    }
    if (lane == 0) {
        atomicMax((int*)(magmax + b0), __float_as_int(mA));
        atomicMax((int*)(magmax + b1), __float_as_int(mB));
    }
}

// ---------------------------------------------------------------------------
// Kernel C: single-pass gradients + all 55 Zernike moments + mask count.
// ---------------------------------------------------------------------------
#define WRED(var, idx)                                                     \
    {                                                                      \
        float r_ = var;                                                    \
        _Pragma("unroll")                                                  \
        for (int off_ = 32; off_; off_ >>= 1) r_ += __shfl_down(r_, off_); \
        if (lane == 0) red[wv * 64 + (idx)] = r_;                          \
    }

__global__ __launch_bounds__(256, 2) void stats_kernel(float* __restrict__ pu) {
    __shared__ float red[4 * 64];
    const int b = blockIdx.y;
    const int k0 = blockIdx.x * 9;
    const float* base = pu + (long long)b * WR * 2048;
    float a00 = 0.f, a11 = 0.f, a20 = 0.f, a22 = 0.f, a31 = 0.f, a33 = 0.f,
          a40 = 0.f, a42 = 0.f, a44 = 0.f, a51 = 0.f, a53 = 0.f, a55 = 0.f,
          a60 = 0.f, a62 = 0.f, a64 = 0.f, a66 = 0.f, a71 = 0.f, a73 = 0.f,
          a75 = 0.f, a77 = 0.f, a80 = 0.f, a82 = 0.f, a84 = 0.f, a86 = 0.f,
          a88 = 0.f, a91 = 0.f, a93 = 0.f, a95 = 0.f, a97 = 0.f, a99 = 0.f;
    float b11 = 0.f, b22 = 0.f, b31 = 0.f, b33 = 0.f, b42 = 0.f, b44 = 0.f,
          b51 = 0.f, b53 = 0.f, b55 = 0.f, b62 = 0.f, b64 = 0.f, b66 = 0.f,
          b71 = 0.f, b73 = 0.f, b75 = 0.f, b77 = 0.f, b82 = 0.f, b84 = 0.f,
          b86 = 0.f, b88 = 0.f, b91 = 0.f, b93 = 0.f, b95 = 0.f, b97 = 0.f,
          b99 = 0.f;
    float sgx = 0.f, sgx2 = 0.f, sgy = 0.f, sgy2 = 0.f, cnt = 0.f;

    for (int kk = 0; kk < 9; ++kk) {
        const int k = k0 + kk;
        const float* rowc = base + (long long)k * 2048;
        const float* rowm = rowc - 2048;
        const float* rowp = rowc + 2048;
        const float xv = -1.0f + (1.0f / 256.0f) * (float)k;
        const float xv2 = xv * xv;
        for (int h = threadIdx.x; h < 1024; h += 256) {
            float v = rowc[h];
            float gx, gy;
            if (k == 0)            gx = rowp[h] - v;
            else if (k == WR - 1)  gx = v - rowm[h];
            else                   gx = 0.5f * (rowp[h] - rowm[h]);
            if (h == 0)            gy = rowc[1] - v;
            else if (h == 1023)    gy = v - rowc[1022];
            else                   gy = 0.5f * (rowc[h + 1] - rowc[h - 1]);
            sgx += gx; sgx2 += gx * gx; sgy += gy; sgy2 += gy * gy;

            const float yv = -1.0f + (2.0f / 1023.0f) * (float)h;
            const float r2 = xv2 + yv * yv;
            if (r2 <= 1.0f) {
                cnt += 1.0f;
                const float rho = sqrtf(r2);
                const float inv = rsqrtf(r2);
                const float c1 = xv * inv;
                const float s1 = yv * inv;
                const float c2 = 2.f * c1 * c1 - 1.f;
                const float c3 = 2.f * c1 * c2 - c1;
                const float c4 = 2.f * c1 * c3 - c2;
                const float c5 = 2.f * c1 * c4 - c3;
                const float c6 = 2.f * c1 * c5 - c4;
                const float c7 = 2.f * c1 * c6 - c5;
                const float c8 = 2.f * c1 * c7 - c6;
                const float c9 = 2.f * c1 * c8 - c7;
                const float s2 = 2.f * c1 * s1;
                const float s3 = 2.f * c1 * s2 - s1;
                const float s4 = 2.f * c1 * s3 - s2;
                const float s5 = 2.f * c1 * s4 - s3;
                const float s6 = 2.f * c1 * s5 - s4;
                const float s7 = 2.f * c1 * s6 - s5;
                const float s8 = 2.f * c1 * s7 - s6;
                const float s9 = 2.f * c1 * s8 - s7;
                const float w0 = v,        w1 = w0 * rho, w2 = w1 * rho, w3 = w2 * rho,
                            w4 = w3 * rho, w5 = w4 * rho, w6 = w5 * rho, w7 = w6 * rho,
                            w8 = w7 * rho, w9 = w8 * rho;
                a00 += w0;
                a11 += w1 * c1;
                a20 += w2;      a22 += w2 * c2;
                a31 += w3 * c1; a33 += w3 * c3;
                a40 += w4;      a42 += w4 * c2; a44 += w4 * c4;
                a51 += w5 * c1; a53 += w5 * c3; a55 += w5 * c5;
                a60 += w6;      a62 += w6 * c2; a64 += w6 * c4; a66 += w6 * c6;
                a71 += w7 * c1; a73 += w7 * c3; a75 += w7 * c5; a77 += w7 * c7;
                a80 += w8;      a82 += w8 * c2; a84 += w8 * c4; a86 += w8 * c6; a88 += w8 * c8;
                a91 += w9 * c1; a93 += w9 * c3; a95 += w9 * c5; a97 += w9 * c7; a99 += w9 * c9;
                b11 += w1 * s1;
                b22 += w2 * s2;
                b31 += w3 * s1; b33 += w3 * s3;
                b42 += w4 * s2; b44 += w4 * s4;
                b51 += w5 * s1; b53 += w5 * s3; b55 += w5 * s5;
                b62 += w6 * s2; b64 += w6 * s4; b66 += w6 * s6;
                b71 += w7 * s1; b73 += w7 * s3; b75 += w7 * s5; b77 += w7 * s7;
                b82 += w8 * s2; b84 += w8 * s4; b86 += w8 * s6; b88 += w8 * s8;
                b91 += w9 * s1; b93 += w9 * s3; b95 += w9 * s5; b97 += w9 * s7; b99 += w9 * s9;
            }
        }
    }

    const int wv = threadIdx.x >> 6, lane = threadIdx.x & 63;
    WRED(a00, 0);  WRED(a11, 1);  WRED(a20, 2);  WRED(a22, 3);  WRED(a31, 4);
    WRED(a33, 5);  WRED(a40, 6);  WRED(a42, 7);  WRED(a44, 8);  WRED(a51, 9);
    WRED(a53, 10); WRED(a55, 11); WRED(a60, 12); WRED(a62, 13); WRED(a64, 14);
    WRED(a66, 15); WRED(a71, 16); WRED(a73, 17); WRED(a75, 18); WRED(a77, 19);
    WRED(a80, 20); WRED(a82, 21); WRED(a84, 22); WRED(a86, 23); WRED(a88, 24);
    WRED(a91, 25); WRED(a93, 26); WRED(a95, 27); WRED(a97, 28); WRED(a99, 29);
    WRED(b11, 30); WRED(b22, 31); WRED(b31, 32); WRED(b33, 33); WRED(b42, 34);
    WRED(b44, 35); WRED(b51, 36); WRED(b53, 37); WRED(b55, 38); WRED(b62, 39);
    WRED(b64, 40); WRED(b66, 41); WRED(b71, 42); WRED(b73, 43); WRED(b75, 44);
    WRED(b77, 45); WRED(b82, 46); WRED(b84, 47); WRED(b86, 48); WRED(b88, 49);
    WRED(b91, 50); WRED(b93, 51); WRED(b95, 52); WRED(b97, 53); WRED(b99, 54);
    WRED(sgx, 55); WRED(sgx2, 56); WRED(sgy, 57); WRED(sgy2, 58); WRED(cnt, 59);
    __syncthreads();
    const int t = threadIdx.x;
    if (t < 60) {
        float s = red[t] + red[64 + t] + red[128 + t] + red[192 + t];
        pu[((long long)(b * 57 + blockIdx.x)) * 2048 + 1024 + t] = s;
    }
}

// ---------------------------------------------------------------------------
// Kernel D: sum 57 block-partials per batch, map moments -> Zernike coeffs,
// finalize stats.
// ---------------------------------------------------------------------------
__device__ int moment_index(int p, int a, int is_cos) {
    int ai = 0;
    for (int pp = 0; pp < 10; ++pp)
        for (int aa = (pp & 1); aa <= pp; aa += 2) {
            if (is_cos && pp == p && aa == a) return ai;
            ++ai;
        }
    for (int pp = 1; pp < 10; ++pp)
        for (int aa = ((pp & 1) ? 1 : 2); aa <= pp; aa += 2) {
            if (!is_cos && pp == p && aa == a) return ai;
            ++ai;
        }
    return 0;
}

__device__ float factf(int n) {
    float f = 1.0f;
    for (int i = 2; i <= n; ++i) f *= (float)i;
    return f;
}

__global__ void finalize_kernel(const float* __restrict__ pu,
                                const float* __restrict__ magmax,
                                float* __restrict__ out) {
    __shared__ float abf[64];
    const int b = blockIdx.x;
    const int j = threadIdx.x;
    if (j < 60) {
        float s = 0.0f;
        for (int i = 0; i < 57; ++i)
            s += pu[((long long)(b * 57 + i)) * 2048 + 1024 + j];
        abf[j] = s;
    }
    __syncthreads();
    if (j >= 60) return;
    const float NF = (float)NPIX;
    float val;
    if (j < 55) {
        int tt = j, n = 0;
        while (tt >= n + 1) { tt -= (n + 1); ++n; }
        int m = -n + 2 * tt;
        int am = m < 0 ? -m : m;
        float s = 0.0f;
        for (int k = 0; k <= (n - am) / 2; ++k) {
            float c = factf(n - k) /
                      (factf(k) * factf((n + am) / 2 - k) * factf((n - am) / 2 - k));
            if (k & 1) c = -c;
            int p = n - 2 * k;
            s += c * abf[moment_index(p, am, m >= 0 ? 1 : 0)];
        }
        val = s / abf[59];
    } else if (j == 55) {
        val = abf[55] / NF;
    } else if (j == 56) {
        val = abf[57] / NF;
    } else if (j == 57) {
        float sum = abf[55], sq = abf[56];
        val = sqrtf(fmaxf(0.0f, (sq - sum * sum / NF) / (NF - 1.0f)));
    } else if (j == 58) {
        float sum = abf[57], sq = abf[58];
        val = sqrtf(fmaxf(0.0f, (sq - sum * sum / NF) / (NF - 1.0f)));
    } else {
        val = magmax[b];
    }
    out[b * 60 + j] = val;
}

// ---------------------------------------------------------------------------
extern "C" void kernel_launch(void* const* d_in, const int* in_sizes, int n_in,
                              void* d_out, int out_size, void* d_ws, size_t ws_size,
                              hipStream_t stream) {
    (void)in_sizes; (void)n_in; (void)out_size; (void)ws_size;
    const float* x = (const float*)d_in[0];
    float* out = (float*)d_out;

    float* magmax = (float*)d_ws;                  // 32 floats (atomicMax target)
    float2* rf2 = (float2*)((char*)d_ws + 16384);  // [B][WR][H] float2 = 134.5 MB

    hipMemsetAsync(d_ws, 0, 16384, stream);
    row_fft_kernel<<<BATCH * 128, 256, 0, stream>>>(x, rf2);
    col_fft_kernel<<<(BATCH * WR) / 4, 128, 0, stream>>>(rf2, magmax);
    dim3 gridC(57, BATCH);
    stats_kernel<<<gridC, 256, 0, stream>>>((float*)rf2);
    finalize_kernel<<<BATCH, 64, 0, stream>>>((const float*)rf2, magmax, out);
}